// Round 1
// baseline (290.471 us; speedup 1.0000x reference)
//
#include <hip/hip_runtime.h>
#include <hip/hip_bf16.h>
#include <stdint.h>

#define NROWS 16384
#define NDIM  1024
#define NLAB  64
#define NC    65
#define CPAD  80

typedef float float4v __attribute__((ext_vector_type(4)));
typedef short short8  __attribute__((ext_vector_type(8)));

// ---- workspace layout (bytes) ----
static constexpr size_t SUMS_B  = 0;          // 80*1024 f32 centroid sums (rows 65..79 stay 0)
static constexpr size_t CNT_B   = 327680;     // 80 u32 counts
static constexpr size_t ACT_B   = 328000;     // 8 u32 active bitfields (16 c's each)
static constexpr size_t SCALE_B = 328032;     // 80 f32  (w / ||abf_c||)
static constexpr size_t WSUM_B  = 328352;     // 1 f32 loss accumulator
static constexpr size_t ZERO_BYTES = 328356;  // memset range (sums..wsum)
static constexpr size_t MASK_B  = 328360;     // 16384 u64 row bitmasks (8-aligned)
static constexpr size_t ABF_B   = 459440;     // 80*1024 bf16 unit anchors (16-aligned)

__device__ __forceinline__ short bf16_of(float f) {
    __hip_bfloat16 h = __float2bfloat16(f);
    return __builtin_bit_cast(short, h);
}

// ---- K1: label bitmasks + counts ----
// 256 blocks x 256 thr; each pass: 4 waves read 4 rows (64 int32 each, coalesced), ballot -> mask.
__global__ __launch_bounds__(256) void k1_labels(const int* __restrict__ label,
                                                 unsigned long long* __restrict__ masks,
                                                 unsigned* __restrict__ counts) {
    __shared__ unsigned cnt[NC];
    int t = threadIdx.x;
    if (t < NC) cnt[t] = 0;
    __syncthreads();
    int wave = t >> 6, lane = t & 63;
    int rowblock = blockIdx.x * 64;
    for (int p = 0; p < 16; ++p) {
        int row = rowblock + p * 4 + wave;
        int v = label[row * NLAB + lane];
        unsigned long long m = __ballot(v != 0);
        unsigned bit = (unsigned)((m >> lane) & 1ull);
        atomicAdd(&cnt[lane], bit);
        if (lane == 0) {
            masks[row] = m;
            if (m == 0ull) atomicAdd(&cnt[64], 1u);
        }
    }
    __syncthreads();
    if (t < NC) atomicAdd(&counts[t], cnt[t]);
}

// ---- K2: centroid sums (lab^T @ x), fp32, predicated FMA over uniform mask bits ----
// grid 256: rc=bid>>2 (64 row-chunks of 256), dc=bid&3 (4 dim-chunks of 256). 1 dim/thread, acc[65].
__global__ __launch_bounds__(256) void k2_sums(const float* __restrict__ x,
                                               const unsigned long long* __restrict__ masks,
                                               float* __restrict__ sums) {
    int t = threadIdx.x;
    int rc = blockIdx.x >> 2, dc = blockIdx.x & 3;
    int d = dc * 256 + t;
    int rowbase = rc * 256;
    float acc[NLAB];
    float acc64 = 0.f;
#pragma unroll
    for (int c = 0; c < NLAB; ++c) acc[c] = 0.f;
    const uint2* m2 = (const uint2*)masks;

    float xv[8]; unsigned lo[8], hi[8];
#pragma unroll
    for (int u = 0; u < 8; ++u) {
        int row = rowbase + u;
        xv[u] = x[(size_t)row * NDIM + d];
        uint2 mm = m2[row];
        lo[u] = __builtin_amdgcn_readfirstlane(mm.x);
        hi[u] = __builtin_amdgcn_readfirstlane(mm.y);
    }
    for (int rr = 0; rr < 256; rr += 8) {
        float nx[8] = {0,0,0,0,0,0,0,0};
        unsigned nlo[8] = {0}, nhi[8] = {0};
        if (rr + 8 < 256) {
#pragma unroll
            for (int u = 0; u < 8; ++u) {
                int row = rowbase + rr + 8 + u;
                nx[u] = x[(size_t)row * NDIM + d];
                uint2 mm = m2[row];
                nlo[u] = __builtin_amdgcn_readfirstlane(mm.x);
                nhi[u] = __builtin_amdgcn_readfirstlane(mm.y);
            }
        }
#pragma unroll
        for (int u = 0; u < 8; ++u) {
#pragma unroll
            for (int c = 0; c < 32; ++c)
                acc[c] = fmaf(((lo[u] >> c) & 1u) ? 1.0f : 0.0f, xv[u], acc[c]);
#pragma unroll
            for (int c = 0; c < 32; ++c)
                acc[32 + c] = fmaf(((hi[u] >> c) & 1u) ? 1.0f : 0.0f, xv[u], acc[32 + c]);
            acc64 += ((lo[u] | hi[u]) == 0u) ? xv[u] : 0.0f;
        }
#pragma unroll
        for (int u = 0; u < 8; ++u) { xv[u] = nx[u]; lo[u] = nlo[u]; hi[u] = nhi[u]; }
    }
#pragma unroll
    for (int c = 0; c < NLAB; ++c) atomicAdd(&sums[c * NDIM + d], acc[c]);
    atomicAdd(&sums[64 * NDIM + d], acc64);
}

// ---- K2b: normalize anchors -> bf16, per-c scale = w/||abf||, active bits ----
__global__ __launch_bounds__(256) void k2b_norm(const float* __restrict__ wptr,
                                                const unsigned* __restrict__ counts,
                                                const float* __restrict__ sums,
                                                unsigned short* __restrict__ abf,
                                                float* __restrict__ scale,
                                                unsigned* __restrict__ act) {
    int c = blockIdx.x, t = threadIdx.x;
    const float* s = sums + c * NDIM;
    unsigned cnt = counts[c];
    float invc = 1.0f / (float)(cnt > 0u ? cnt : 1u);
    float ss = 0.f;
    for (int d = t; d < NDIM; d += 256) { float a = s[d] * invc; ss += a * a; }
    __shared__ float red[4];
#pragma unroll
    for (int m = 32; m >= 1; m >>= 1) ss += __shfl_xor(ss, m, 64);
    if ((t & 63) == 0) red[t >> 6] = ss;
    __syncthreads();
    ss = red[0] + red[1] + red[2] + red[3];
    __syncthreads();
    // reference: anchor = sum/max(cnt,1); an = max(||anchor||, eps)
    float denom = fmaxf(sqrtf(ss), 1e-8f);
    float rinv = invc / denom;
    float nb2 = 0.f;
    for (int d = t; d < NDIM; d += 256) {
        float ah = s[d] * rinv;
        __hip_bfloat16 h = __float2bfloat16(ah);
        abf[c * NDIM + d] = __builtin_bit_cast(unsigned short, h);
        float hv = __bfloat162float(h);
        nb2 += hv * hv;
    }
#pragma unroll
    for (int m = 32; m >= 1; m >>= 1) nb2 += __shfl_xor(nb2, m, 64);
    if ((t & 63) == 0) red[t >> 6] = nb2;
    __syncthreads();
    if (t == 0) {
        float n2 = red[0] + red[1] + red[2] + red[3];
        scale[c] = (n2 > 0.f) ? (wptr[0] / sqrtf(n2)) : 0.f;
        if (cnt > 0u) atomicOr(&act[c >> 4], 1u << (c & 15));
    }
}

// ---- K3: cos GEMM via bf16 MFMA + online row norms + log-softmax + pair loss ----
// 256 blocks x 4 waves; wave = one 16-row tile x 5 ctiles (C padded to 80).
__global__ __launch_bounds__(256) void k3_loss(const float* __restrict__ x,
                                               const unsigned short* __restrict__ abf,
                                               const unsigned long long* __restrict__ masks,
                                               const unsigned* __restrict__ act,
                                               const float* __restrict__ scale,
                                               const float* __restrict__ bptr,
                                               float* __restrict__ wsum) {
    int t = threadIdx.x, wave = t >> 6, lane = t & 63;
    int q = lane >> 4, col = lane & 15;
    int rt = blockIdx.x * 4 + wave;
    int rowbase = rt * 16;
    float bv = bptr[0];
    float sc[5]; unsigned ab[5];
#pragma unroll
    for (int ct = 0; ct < 5; ++ct) { sc[ct] = scale[ct * 16 + col]; ab[ct] = act[ct]; }
    float4v acc[5];
#pragma unroll
    for (int ct = 0; ct < 5; ++ct) acc[ct] = (float4v){0.f, 0.f, 0.f, 0.f};
    float sq = 0.f;
    const float* xrow = x + (size_t)(rowbase + col) * NDIM + q * 8;
#pragma unroll 4
    for (int ks = 0; ks < 32; ++ks) {
        int kb = ks * 32;
        float4 f0 = *(const float4*)(xrow + kb);
        float4 f1 = *(const float4*)(xrow + kb + 4);
        sq += f0.x * f0.x + f0.y * f0.y + f0.z * f0.z + f0.w * f0.w
            + f1.x * f1.x + f1.y * f1.y + f1.z * f1.z + f1.w * f1.w;
        short8 af;
        af[0] = bf16_of(f0.x); af[1] = bf16_of(f0.y); af[2] = bf16_of(f0.z); af[3] = bf16_of(f0.w);
        af[4] = bf16_of(f1.x); af[5] = bf16_of(f1.y); af[6] = bf16_of(f1.z); af[7] = bf16_of(f1.w);
#pragma unroll
        for (int ct = 0; ct < 5; ++ct) {
            const unsigned short* bp = abf + (size_t)(ct * 16 + col) * NDIM + kb + q * 8;
            int4 raw = *(const int4*)bp;
            short8 bf = __builtin_bit_cast(short8, raw);
            acc[ct] = __builtin_amdgcn_mfma_f32_16x16x32_bf16(af, bf, acc[ct], 0, 0, 0);
        }
    }
    // full ||x||^2 per row: reduce over the 4 k-quadrant lanes
    sq += __shfl_xor(sq, 16, 64);
    sq += __shfl_xor(sq, 32, 64);   // lane holds xn2 of row rowbase+(lane&15)

    float contrib = 0.f;
#pragma unroll
    for (int reg = 0; reg < 4; ++reg) {
        int rl = q * 4 + reg;
        int row = rowbase + rl;
        float xn2 = __shfl(sq, (lane & 48) | rl, 64);
        float inv = 1.0f / fmaxf(sqrtf(xn2), 1e-8f);
        unsigned long long mask = masks[row];
        float v[5]; float lmax = -1e30f;
#pragma unroll
        for (int ct = 0; ct < 5; ++ct) {
            float lg = acc[ct][reg] * sc[ct] * inv + bv;   // w*cos + b
            bool a = (ab[ct] >> col) & 1u;
            v[ct] = a ? lg : -1e30f;
            lmax = fmaxf(lmax, v[ct]);
        }
#pragma unroll
        for (int m = 1; m < 16; m <<= 1) lmax = fmaxf(lmax, __shfl_xor(lmax, m, 16));
        float es = 0.f;
#pragma unroll
        for (int ct = 0; ct < 5; ++ct) es += expf(v[ct] - lmax);
#pragma unroll
        for (int m = 1; m < 16; m <<= 1) es += __shfl_xor(es, m, 16);
        float lse = lmax + logf(es);
        float ps = 0.f;
#pragma unroll
        for (int ct = 0; ct < 5; ++ct) {
            int c = ct * 16 + col;
            bool pos = (c < 64) ? (((mask >> c) & 1ull) != 0ull)
                                : ((c == 64) ? (mask == 0ull) : false);
            ps += pos ? v[ct] : 0.f;
        }
#pragma unroll
        for (int m = 1; m < 16; m <<= 1) ps += __shfl_xor(ps, m, 16);
        float npos = mask ? (float)__popcll(mask) : 1.0f;
        float crow = ps - npos * lse;
        if (col == 0) contrib += crow;
    }
#pragma unroll
    for (int m = 1; m < 64; m <<= 1) contrib += __shfl_xor(contrib, m, 64);
    if (lane == 0) atomicAdd(wsum, contrib);
}

// ---- K4: loss = -sum(logp over positive pairs) / n_pairs ----
__global__ void k4_final(const unsigned* __restrict__ counts,
                         const float* __restrict__ wsum,
                         float* __restrict__ out) {
    if (threadIdx.x == 0 && blockIdx.x == 0) {
        float np = 0.f;
        for (int c = 0; c < NC; ++c) np += (float)counts[c];
        out[0] = -wsum[0] / np;
    }
}

extern "C" void kernel_launch(void* const* d_in, const int* in_sizes, int n_in,
                              void* d_out, int out_size, void* d_ws, size_t ws_size,
                              hipStream_t stream) {
    (void)in_sizes; (void)n_in; (void)out_size; (void)ws_size;
    const float* x = (const float*)d_in[0];
    const int* label = (const int*)d_in[1];
    const float* w = (const float*)d_in[2];
    const float* b = (const float*)d_in[3];

    char* ws = (char*)d_ws;
    float* sums = (float*)(ws + SUMS_B);
    unsigned* counts = (unsigned*)(ws + CNT_B);
    unsigned* act = (unsigned*)(ws + ACT_B);
    float* scale = (float*)(ws + SCALE_B);
    float* wsum = (float*)(ws + WSUM_B);
    unsigned long long* masks = (unsigned long long*)(ws + MASK_B);
    unsigned short* abf = (unsigned short*)(ws + ABF_B);

    hipMemsetAsync(d_ws, 0, ZERO_BYTES, stream);
    hipLaunchKernelGGL(k1_labels, dim3(256), dim3(256), 0, stream, label, masks, counts);
    hipLaunchKernelGGL(k2_sums, dim3(256), dim3(256), 0, stream, x, masks, sums);
    hipLaunchKernelGGL(k2b_norm, dim3(CPAD), dim3(256), 0, stream, w, counts, sums, abf, scale, act);
    hipLaunchKernelGGL(k3_loss, dim3(256), dim3(256), 0, stream, x, abf, masks, act, scale, b, wsum);
    hipLaunchKernelGGL(k4_final, dim3(1), dim3(64), 0, stream, counts, wsum, (float*)d_out);
}

// Round 2
// 280.980 us; speedup vs baseline: 1.0338x; 1.0338x over previous
//
#include <hip/hip_runtime.h>
#include <hip/hip_bf16.h>
#include <stdint.h>

#define NROWS 16384
#define NDIM  1024
#define NLAB  64
#define NC    65
#define CPAD  80

typedef float float4v __attribute__((ext_vector_type(4)));
typedef short short8  __attribute__((ext_vector_type(8)));

// ---- workspace layout (bytes) ----
static constexpr size_t CNT_B   = 0;       // 80 u32 counts
static constexpr size_t ACT_B   = 320;     // 8 u32 active bitfields
static constexpr size_t SCALE_B = 352;     // 80 f32 (w/||abf_c||)
static constexpr size_t WSUM_B  = 672;     // 1 f32 loss accumulator
static constexpr size_t ZERO_BYTES = 676;  // memset range
static constexpr size_t MASK_B  = 1024;    // 16384 u64 row bitmasks
static constexpr size_t ABF_B   = 132096;  // 80*1024 bf16 unit anchors
static constexpr size_t PART_B  = 296192;  // slices*80*1024 f32 partial sums

__device__ __forceinline__ unsigned short bf16u(float f) {
    __hip_bfloat16 h = __float2bfloat16(f);
    return __builtin_bit_cast(unsigned short, h);
}
__device__ __forceinline__ short bf16s(float f) {
    __hip_bfloat16 h = __float2bfloat16(f);
    return __builtin_bit_cast(short, h);
}

// ---- K1: label bitmasks + counts ----
__global__ __launch_bounds__(256) void k1_labels(const int* __restrict__ label,
                                                 unsigned long long* __restrict__ masks,
                                                 unsigned* __restrict__ counts) {
    __shared__ unsigned cnt[NC];
    int t = threadIdx.x;
    if (t < NC) cnt[t] = 0;
    __syncthreads();
    int wave = t >> 6, lane = t & 63;
    int rowblock = blockIdx.x * 64;
    for (int p = 0; p < 16; ++p) {
        int row = rowblock + p * 4 + wave;
        int v = label[row * NLAB + lane];
        unsigned long long m = __ballot(v != 0);
        unsigned bit = (unsigned)((m >> lane) & 1ull);
        atomicAdd(&cnt[lane], bit);
        if (lane == 0) {
            masks[row] = m;
            if (m == 0ull) atomicAdd(&cnt[64], 1u);
        }
    }
    __syncthreads();
    if (t < NC) atomicAdd(&counts[t], cnt[t]);
}

// ---- K2: centroid partial sums. wave = (slice, dimchunk 0..7, cgroup 0..1) ----
// 33 float2 accumulators/thread (register-resident), no atomics: each wave
// writes a disjoint piece of partial[slice][c][d].
__global__ __launch_bounds__(256, 2) void k2_sums(const float* __restrict__ x,
                                                  const uint2* __restrict__ masks2,
                                                  float* __restrict__ partial,
                                                  int slices) {
    int t = threadIdx.x;
    int wid = blockIdx.x * 4 + (t >> 6);
    int lane = t & 63;
    int slice = wid >> 4;
    int sub = wid & 15;
    int cg = sub & 1;
    int dch = sub >> 1;                 // 0..7
    int d0 = dch * 128 + lane * 2;
    int rows = NROWS / slices;
    int row0 = slice * rows;

    float2 a[32];
    float2 a64 = make_float2(0.f, 0.f);
#pragma unroll
    for (int i = 0; i < 32; ++i) a[i] = make_float2(0.f, 0.f);

    for (int r = 0; r < rows; ++r) {
        int row = row0 + r;
        float2 xv = *(const float2*)(x + (size_t)row * NDIM + d0);
        uint2 mm = masks2[row];
        unsigned lo = __builtin_amdgcn_readfirstlane(mm.x);
        unsigned hi = __builtin_amdgcn_readfirstlane(mm.y);
        unsigned bits = cg ? hi : lo;
#pragma unroll
        for (int c = 0; c < 32; ++c) {
            float sel = ((bits >> c) & 1u) ? 1.0f : 0.0f;
            a[c].x = fmaf(sel, xv.x, a[c].x);
            a[c].y = fmaf(sel, xv.y, a[c].y);
        }
        if (cg == 0) {
            float sel = ((lo | hi) == 0u) ? 1.0f : 0.0f;
            a64.x = fmaf(sel, xv.x, a64.x);
            a64.y = fmaf(sel, xv.y, a64.y);
        }
    }
    float* base = partial + (size_t)slice * CPAD * NDIM;
#pragma unroll
    for (int c = 0; c < 32; ++c)
        *(float2*)(base + (size_t)(cg * 32 + c) * NDIM + d0) = a[c];
    if (cg == 0)
        *(float2*)(base + (size_t)64 * NDIM + d0) = a64;
}

// ---- K2b: reduce partials, normalize anchors -> bf16, per-c scale, active bits ----
__global__ __launch_bounds__(256) void k2b_norm(const float* __restrict__ wptr,
                                                const unsigned* __restrict__ counts,
                                                const float* __restrict__ partial,
                                                int slices,
                                                unsigned short* __restrict__ abf,
                                                float* __restrict__ scale,
                                                unsigned* __restrict__ act) {
    int c = blockIdx.x, t = threadIdx.x;
    if (c >= NC) {   // pad rows 65..79: zero bf16 anchors so MFMA B-frags are 0
        *(uint2*)(abf + (size_t)c * NDIM + t * 4) = make_uint2(0u, 0u);
        if (t == 0) scale[c] = 0.f;
        return;
    }
    int d0 = t * 4;
    float4 s = make_float4(0.f, 0.f, 0.f, 0.f);
    for (int sl = 0; sl < slices; ++sl) {
        float4 p = *(const float4*)(partial + (size_t)sl * CPAD * NDIM + (size_t)c * NDIM + d0);
        s.x += p.x; s.y += p.y; s.z += p.z; s.w += p.w;
    }
    unsigned cnt = counts[c];
    float invc = 1.0f / (float)(cnt > 0u ? cnt : 1u);
    float ax = s.x * invc, ay = s.y * invc, az = s.z * invc, aw = s.w * invc;
    float ss = ax * ax + ay * ay + az * az + aw * aw;

    __shared__ float red[8];
#pragma unroll
    for (int m = 32; m >= 1; m >>= 1) ss += __shfl_xor(ss, m, 64);
    if ((t & 63) == 0) red[t >> 6] = ss;
    __syncthreads();
    ss = red[0] + red[1] + red[2] + red[3];

    float denom = fmaxf(sqrtf(ss), 1e-8f);   // an = max(||anchor||, eps)
    float rinv = invc / denom;

    unsigned short h0 = bf16u(s.x * rinv), h1 = bf16u(s.y * rinv);
    unsigned short h2 = bf16u(s.z * rinv), h3 = bf16u(s.w * rinv);
    unsigned p0 = ((unsigned)h1 << 16) | h0;
    unsigned p1 = ((unsigned)h3 << 16) | h2;
    *(uint2*)(abf + (size_t)c * NDIM + d0) = make_uint2(p0, p1);

    float f0 = __bfloat162float(__builtin_bit_cast(__hip_bfloat16, h0));
    float f1 = __bfloat162float(__builtin_bit_cast(__hip_bfloat16, h1));
    float f2 = __bfloat162float(__builtin_bit_cast(__hip_bfloat16, h2));
    float f3 = __bfloat162float(__builtin_bit_cast(__hip_bfloat16, h3));
    float nb2 = f0 * f0 + f1 * f1 + f2 * f2 + f3 * f3;
#pragma unroll
    for (int m = 32; m >= 1; m >>= 1) nb2 += __shfl_xor(nb2, m, 64);
    if ((t & 63) == 0) red[4 + (t >> 6)] = nb2;
    __syncthreads();
    if (t == 0) {
        float n2 = red[4] + red[5] + red[6] + red[7];
        scale[c] = (n2 > 0.f) ? (wptr[0] / sqrtf(n2)) : 0.f;
        if (cnt > 0u) atomicOr(&act[c >> 4], 1u << (c & 15));
    }
}

// ---- K3: cos GEMM via bf16 MFMA, k-split x2 (2 waves per 16-row tile) ----
__global__ __launch_bounds__(256) void k3_loss(const float* __restrict__ x,
                                               const unsigned short* __restrict__ abf,
                                               const unsigned long long* __restrict__ masks,
                                               const unsigned* __restrict__ act,
                                               const float* __restrict__ scale,
                                               const float* __restrict__ bptr,
                                               float* __restrict__ wsum) {
    __shared__ float xch[2][64 * 21];
    int t = threadIdx.x, wave = t >> 6, lane = t & 63;
    int q = lane >> 4, col = lane & 15;
    int p = wave >> 1, kh = wave & 1;
    int rt = blockIdx.x * 2 + p;
    int rowbase = rt * 16;

    float4v acc[5];
#pragma unroll
    for (int ct = 0; ct < 5; ++ct) acc[ct] = (float4v){0.f, 0.f, 0.f, 0.f};
    float sq = 0.f;
    const float* xrow = x + (size_t)(rowbase + col) * NDIM + q * 8;
    int kb0 = kh * 512;
#pragma unroll 4
    for (int ks = 0; ks < 16; ++ks) {
        int kb = kb0 + ks * 32;
        float4 f0 = *(const float4*)(xrow + kb);
        float4 f1 = *(const float4*)(xrow + kb + 4);
        sq += f0.x * f0.x + f0.y * f0.y + f0.z * f0.z + f0.w * f0.w
            + f1.x * f1.x + f1.y * f1.y + f1.z * f1.z + f1.w * f1.w;
        short8 af;
        af[0] = bf16s(f0.x); af[1] = bf16s(f0.y); af[2] = bf16s(f0.z); af[3] = bf16s(f0.w);
        af[4] = bf16s(f1.x); af[5] = bf16s(f1.y); af[6] = bf16s(f1.z); af[7] = bf16s(f1.w);
#pragma unroll
        for (int ct = 0; ct < 5; ++ct) {
            const unsigned short* bp = abf + (size_t)(ct * 16 + col) * NDIM + kb + q * 8;
            int4 raw = *(const int4*)bp;
            short8 bf = __builtin_bit_cast(short8, raw);
            acc[ct] = __builtin_amdgcn_mfma_f32_16x16x32_bf16(af, bf, acc[ct], 0, 0, 0);
        }
    }
    // per-wave partial ||x||^2: reduce over the k-quadrant lanes
    sq += __shfl_xor(sq, 16, 64);
    sq += __shfl_xor(sq, 32, 64);   // lane holds half-row sq of row rowbase+(lane&15)

    // combine the two k-halves via LDS
    if (kh == 1) {
        float* dst = &xch[p][lane * 21];
#pragma unroll
        for (int ct = 0; ct < 5; ++ct)
#pragma unroll
            for (int r = 0; r < 4; ++r) dst[ct * 4 + r] = acc[ct][r];
        dst[20] = sq;
    }
    __syncthreads();
    if (kh == 1) return;           // no further barriers below
    {
        const float* src = &xch[p][lane * 21];
#pragma unroll
        for (int ct = 0; ct < 5; ++ct)
#pragma unroll
            for (int r = 0; r < 4; ++r) acc[ct][r] += src[ct * 4 + r];
        sq += src[20];
    }

    float bv = bptr[0];
    float sc[5]; unsigned ab[5];
#pragma unroll
    for (int ct = 0; ct < 5; ++ct) { sc[ct] = scale[ct * 16 + col]; ab[ct] = act[ct]; }

    float contrib = 0.f;
#pragma unroll
    for (int reg = 0; reg < 4; ++reg) {
        int rl = q * 4 + reg;
        int row = rowbase + rl;
        float xn2 = __shfl(sq, (lane & 48) | rl, 64);
        float inv = 1.0f / fmaxf(sqrtf(xn2), 1e-8f);
        unsigned long long mask = masks[row];
        float v[5]; float lmax = -1e30f;
#pragma unroll
        for (int ct = 0; ct < 5; ++ct) {
            float lg = acc[ct][reg] * sc[ct] * inv + bv;   // w*cos + b
            bool a = (ab[ct] >> col) & 1u;
            v[ct] = a ? lg : -1e30f;
            lmax = fmaxf(lmax, v[ct]);
        }
#pragma unroll
        for (int m = 1; m < 16; m <<= 1) lmax = fmaxf(lmax, __shfl_xor(lmax, m, 16));
        float es = 0.f;
#pragma unroll
        for (int ct = 0; ct < 5; ++ct) es += expf(v[ct] - lmax);
#pragma unroll
        for (int m = 1; m < 16; m <<= 1) es += __shfl_xor(es, m, 16);
        float lse = lmax + logf(es);
        float ps = 0.f;
#pragma unroll
        for (int ct = 0; ct < 5; ++ct) {
            int c = ct * 16 + col;
            bool pos = (c < 64) ? (((mask >> c) & 1ull) != 0ull)
                                : ((c == 64) ? (mask == 0ull) : false);
            ps += pos ? v[ct] : 0.f;
        }
#pragma unroll
        for (int m = 1; m < 16; m <<= 1) ps += __shfl_xor(ps, m, 16);
        float npos = mask ? (float)__popcll(mask) : 1.0f;
        float crow = ps - npos * lse;
        if (col == 0) contrib += crow;
    }
#pragma unroll
    for (int m = 1; m < 64; m <<= 1) contrib += __shfl_xor(contrib, m, 64);
    if (lane == 0) atomicAdd(wsum, contrib);
}

// ---- K4: loss = -sum(logp over positive pairs) / n_pairs ----
__global__ void k4_final(const unsigned* __restrict__ counts,
                         const float* __restrict__ wsum,
                         float* __restrict__ out) {
    if (threadIdx.x == 0 && blockIdx.x == 0) {
        float np = 0.f;
        for (int c = 0; c < NC; ++c) np += (float)counts[c];
        out[0] = -wsum[0] / np;
    }
}

extern "C" void kernel_launch(void* const* d_in, const int* in_sizes, int n_in,
                              void* d_out, int out_size, void* d_ws, size_t ws_size,
                              hipStream_t stream) {
    (void)in_sizes; (void)n_in; (void)out_size;
    const float* x = (const float*)d_in[0];
    const int* label = (const int*)d_in[1];
    const float* w = (const float*)d_in[2];
    const float* b = (const float*)d_in[3];

    char* ws = (char*)d_ws;
    unsigned* counts = (unsigned*)(ws + CNT_B);
    unsigned* act = (unsigned*)(ws + ACT_B);
    float* scale = (float*)(ws + SCALE_B);
    float* wsum = (float*)(ws + WSUM_B);
    unsigned long long* masks = (unsigned long long*)(ws + MASK_B);
    unsigned short* abf = (unsigned short*)(ws + ABF_B);
    float* partial = (float*)(ws + PART_B);

    // adaptive slice count so partials fit the workspace (deterministic per ws_size)
    int slices = 128;
    while (slices > 16 && PART_B + (size_t)slices * CPAD * NDIM * 4 > ws_size) slices >>= 1;

    hipMemsetAsync(d_ws, 0, ZERO_BYTES, stream);
    hipLaunchKernelGGL(k1_labels, dim3(256), dim3(256), 0, stream, label, masks, counts);
    hipLaunchKernelGGL(k2_sums, dim3(slices * 4), dim3(256), 0, stream,
                       x, (const uint2*)masks, partial, slices);
    hipLaunchKernelGGL(k2b_norm, dim3(CPAD), dim3(256), 0, stream,
                       w, counts, partial, slices, abf, scale, act);
    hipLaunchKernelGGL(k3_loss, dim3(512), dim3(256), 0, stream,
                       x, abf, masks, act, scale, b, wsum);
    hipLaunchKernelGGL(k4_final, dim3(1), dim3(64), 0, stream, counts, wsum, (float*)d_out);
}

// Round 3
// 184.025 us; speedup vs baseline: 1.5784x; 1.5269x over previous
//
#include <hip/hip_runtime.h>
#include <hip/hip_bf16.h>
#include <stdint.h>

#define NROWS 16384
#define NDIM  1024
#define NLAB  64
#define NC    65
#define CPAD  80

typedef float float4v __attribute__((ext_vector_type(4)));
typedef short short8  __attribute__((ext_vector_type(8)));

// ---- workspace layout (bytes) ----
static constexpr size_t CNT_B   = 0;        // 80 u32 counts
static constexpr size_t ACT_B   = 320;      // 8 u32 active bitfields
static constexpr size_t SCALE_B = 352;      // 80 f32 (w/||abf_c||)
static constexpr size_t WSUM_B  = 672;      // 1 f32 loss accumulator
static constexpr size_t ZERO_BYTES = 676;   // memset range
static constexpr size_t MASK_B  = 1024;     // 16384 u64 row bitmasks
static constexpr size_t ABF_B   = 132096;   // 80*1024 bf16 unit anchors
static constexpr size_t LABT_B  = 295936;   // 80*16384 bf16 lab^T (A-operand)
static constexpr size_t PART_B  = 2917376;  // kslices*80*1024 f32 partials

__device__ __forceinline__ unsigned short bf16u(float f) {
    __hip_bfloat16 h = __float2bfloat16(f);
    return __builtin_bit_cast(unsigned short, h);
}
__device__ __forceinline__ unsigned pk2(float a, float b) {
    return (unsigned)bf16u(a) | ((unsigned)bf16u(b) << 16);
}

// ---- K1: label bitmasks + counts + labT (bf16 0/1 matrix, c-major) ----
__global__ __launch_bounds__(256) void k1_labels(const int* __restrict__ label,
                                                 unsigned long long* __restrict__ masks,
                                                 unsigned* __restrict__ counts,
                                                 unsigned short* __restrict__ labT) {
    __shared__ unsigned cnt[NC];
    __shared__ unsigned long long smask[64];
    int t = threadIdx.x;
    if (t < NC) cnt[t] = 0;
    __syncthreads();
    int wave = t >> 6, lane = t & 63;
    int rowblock = blockIdx.x * 64;
    for (int p = 0; p < 16; ++p) {
        int row = rowblock + p * 4 + wave;
        int v = label[row * NLAB + lane];
        unsigned long long m = __ballot(v != 0);
        unsigned bit = (unsigned)((m >> lane) & 1ull);
        atomicAdd(&cnt[lane], bit);
        if (lane == 0) {
            masks[row] = m;
            smask[p * 4 + wave] = m;
            if (m == 0ull) atomicAdd(&cnt[64], 1u);
        }
    }
    __syncthreads();
    if (t < NC) atomicAdd(&counts[t], cnt[t]);
    // labT[c][row] for this 64-row block: 80 c x 32 row-pairs, bf16{0,1} packed 2/u32
    for (int job = t; job < CPAD * 32; job += 256) {
        int c = job >> 5, rp = job & 31;
        unsigned long long m0 = smask[rp * 2], m1 = smask[rp * 2 + 1];
        unsigned b0, b1;
        if (c < 64)      { b0 = (unsigned)((m0 >> c) & 1ull); b1 = (unsigned)((m1 >> c) & 1ull); }
        else if (c == 64){ b0 = (m0 == 0ull); b1 = (m1 == 0ull); }
        else             { b0 = 0u; b1 = 0u; }
        unsigned pk = (b0 ? 0x3F80u : 0u) | (b1 ? 0x3F800000u : 0u);
        *(unsigned*)(labT + (size_t)c * NROWS + rowblock + rp * 2) = pk;
    }
}

// ---- K2: sums = labT @ x via bf16 MFMA. block = (dgroup of 64 d) x (kslice) ----
// wave = one 16-d tile; 5 ctiles x float4 acc per wave. A direct from global
// (labT is already fragment-layout), B = x^T staged bf16 in LDS.
__global__ __launch_bounds__(256) void k2_sums(const float* __restrict__ x,
                                               const unsigned short* __restrict__ labT,
                                               float* __restrict__ partial,
                                               int kslices) {
    __shared__ unsigned short xT[64][40];   // [d][32 rows + 8 pad], stride 80 B
    int t = threadIdx.x, wave = t >> 6, lane = t & 63;
    int q = lane >> 4, col = lane & 15;
    int dg = blockIdx.x & 15, ks = blockIdx.x >> 4;
    int rowsper = NROWS / kslices;
    int row0 = ks * rowsper;
    int d0 = dg * 64;
    int sd = t & 63, rblk = t >> 6;        // staging: one d, 8 rows

    float4v acc[5];
#pragma unroll
    for (int ct = 0; ct < 5; ++ct) acc[ct] = (float4v){0.f, 0.f, 0.f, 0.f};

    int steps = rowsper >> 5;
    for (int step = 0; step < steps; ++step) {
        int rbase = row0 + step * 32;
        float v[8];
#pragma unroll
        for (int j = 0; j < 8; ++j)
            v[j] = x[(size_t)(rbase + rblk * 8 + j) * NDIM + d0 + sd];
        __syncthreads();                   // prior frag reads done
        uint4 w;
        w.x = pk2(v[0], v[1]); w.y = pk2(v[2], v[3]);
        w.z = pk2(v[4], v[5]); w.w = pk2(v[6], v[7]);
        *(uint4*)&xT[sd][rblk * 8] = w;
        __syncthreads();
        int4 braw = *(const int4*)&xT[wave * 16 + col][q * 8];
        short8 bf = __builtin_bit_cast(short8, braw);
#pragma unroll
        for (int ct = 0; ct < 5; ++ct) {
            int4 araw = *(const int4*)(labT + (size_t)(ct * 16 + col) * NROWS + rbase + q * 8);
            short8 af = __builtin_bit_cast(short8, araw);
            acc[ct] = __builtin_amdgcn_mfma_f32_16x16x32_bf16(af, bf, acc[ct], 0, 0, 0);
        }
    }
    // D layout: c = q*4+reg (+16*ct), d = d0 + wave*16 + col
    float* pb = partial + (size_t)ks * CPAD * NDIM;
#pragma unroll
    for (int ct = 0; ct < 5; ++ct)
#pragma unroll
        for (int reg = 0; reg < 4; ++reg)
            pb[(size_t)(ct * 16 + q * 4 + reg) * NDIM + d0 + wave * 16 + col] = acc[ct][reg];
}

// ---- K2b: reduce partials, normalize anchors -> bf16, per-c scale, active bits ----
__global__ __launch_bounds__(256) void k2b_norm(const float* __restrict__ wptr,
                                                const unsigned* __restrict__ counts,
                                                const float* __restrict__ partial,
                                                int kslices,
                                                unsigned short* __restrict__ abf,
                                                float* __restrict__ scale,
                                                unsigned* __restrict__ act) {
    int c = blockIdx.x, t = threadIdx.x;
    if (c >= NC) {
        *(uint2*)(abf + (size_t)c * NDIM + t * 4) = make_uint2(0u, 0u);
        if (t == 0) scale[c] = 0.f;
        return;
    }
    int d0 = t * 4;
    float4 s = make_float4(0.f, 0.f, 0.f, 0.f);
    for (int sl = 0; sl < kslices; ++sl) {
        float4 p = *(const float4*)(partial + (size_t)sl * CPAD * NDIM + (size_t)c * NDIM + d0);
        s.x += p.x; s.y += p.y; s.z += p.z; s.w += p.w;
    }
    unsigned cnt = counts[c];
    float invc = 1.0f / (float)(cnt > 0u ? cnt : 1u);
    float ax = s.x * invc, ay = s.y * invc, az = s.z * invc, aw = s.w * invc;
    float ss = ax * ax + ay * ay + az * az + aw * aw;

    __shared__ float red[8];
#pragma unroll
    for (int m = 32; m >= 1; m >>= 1) ss += __shfl_xor(ss, m, 64);
    if ((t & 63) == 0) red[t >> 6] = ss;
    __syncthreads();
    ss = red[0] + red[1] + red[2] + red[3];

    float denom = fmaxf(sqrtf(ss), 1e-8f);
    float rinv = invc / denom;

    unsigned short h0 = bf16u(s.x * rinv), h1 = bf16u(s.y * rinv);
    unsigned short h2 = bf16u(s.z * rinv), h3 = bf16u(s.w * rinv);
    *(uint2*)(abf + (size_t)c * NDIM + d0) =
        make_uint2(((unsigned)h1 << 16) | h0, ((unsigned)h3 << 16) | h2);

    float f0 = __bfloat162float(__builtin_bit_cast(__hip_bfloat16, h0));
    float f1 = __bfloat162float(__builtin_bit_cast(__hip_bfloat16, h1));
    float f2 = __bfloat162float(__builtin_bit_cast(__hip_bfloat16, h2));
    float f3 = __bfloat162float(__builtin_bit_cast(__hip_bfloat16, h3));
    float nb2 = f0 * f0 + f1 * f1 + f2 * f2 + f3 * f3;
#pragma unroll
    for (int m = 32; m >= 1; m >>= 1) nb2 += __shfl_xor(nb2, m, 64);
    if ((t & 63) == 0) red[4 + (t >> 6)] = nb2;
    __syncthreads();
    if (t == 0) {
        float n2 = red[4] + red[5] + red[6] + red[7];
        scale[c] = (n2 > 0.f) ? (wptr[0] / sqrtf(n2)) : 0.f;
        if (cnt > 0u) atomicOr(&act[c >> 4], 1u << (c & 15));
    }
}

// ---- K3: cos GEMM, x staged coalesced -> bf16 LDS; k-split x2; fused softmax loss ----
__global__ __launch_bounds__(256) void k3_loss(const float* __restrict__ x,
                                               const unsigned short* __restrict__ abf,
                                               const unsigned long long* __restrict__ masks,
                                               const unsigned* __restrict__ act,
                                               const float* __restrict__ scale,
                                               const float* __restrict__ bptr,
                                               float* __restrict__ wsum) {
    __shared__ unsigned short xs[32][72];   // [row][64 k + 8 pad], stride 144 B
    __shared__ float xn2[32];
    __shared__ float xch[2][64 * 20];
    int t = threadIdx.x, wave = t >> 6, lane = t & 63;
    int q = lane >> 4, col = lane & 15;
    int p = wave >> 1, kh = wave & 1;
    int blockrow0 = blockIdx.x * 32;
    int rowbase = blockrow0 + p * 16;
    int srow = t >> 3, skoff = (t & 7) * 8;

    float4v acc[5];
#pragma unroll
    for (int ct = 0; ct < 5; ++ct) acc[ct] = (float4v){0.f, 0.f, 0.f, 0.f};
    float sq = 0.f;
    const float* xsrc = x + (size_t)(blockrow0 + srow) * NDIM + skoff;

    for (int step = 0; step < 16; ++step) {
        int k0 = step * 64;
        float4 f0 = *(const float4*)(xsrc + k0);
        float4 f1 = *(const float4*)(xsrc + k0 + 4);
        __syncthreads();                   // prior frag reads done
        sq += f0.x * f0.x + f0.y * f0.y + f0.z * f0.z + f0.w * f0.w
            + f1.x * f1.x + f1.y * f1.y + f1.z * f1.z + f1.w * f1.w;
        uint4 w;
        w.x = pk2(f0.x, f0.y); w.y = pk2(f0.z, f0.w);
        w.z = pk2(f1.x, f1.y); w.w = pk2(f1.z, f1.w);
        *(uint4*)&xs[srow][skoff] = w;
        __syncthreads();
        int kk = kh * 32 + q * 8;
        int4 araw = *(const int4*)&xs[p * 16 + col][kk];
        short8 af = __builtin_bit_cast(short8, araw);
#pragma unroll
        for (int ct = 0; ct < 5; ++ct) {
            int4 braw = *(const int4*)(abf + (size_t)(ct * 16 + col) * NDIM + k0 + kk);
            short8 bf = __builtin_bit_cast(short8, braw);
            acc[ct] = __builtin_amdgcn_mfma_f32_16x16x32_bf16(af, bf, acc[ct], 0, 0, 0);
        }
    }
    // exact fp32 row norms: 8 staging threads per row
#pragma unroll
    for (int m = 1; m < 8; m <<= 1) sq += __shfl_xor(sq, m, 8);
    if ((t & 7) == 0) xn2[srow] = sq;
    // combine k-halves
    if (kh == 1) {
        float* dst = &xch[p][lane * 20];
#pragma unroll
        for (int ct = 0; ct < 5; ++ct)
#pragma unroll
            for (int r = 0; r < 4; ++r) dst[ct * 4 + r] = acc[ct][r];
    }
    __syncthreads();
    if (kh == 1) return;
    {
        const float* src = &xch[p][lane * 20];
#pragma unroll
        for (int ct = 0; ct < 5; ++ct)
#pragma unroll
            for (int r = 0; r < 4; ++r) acc[ct][r] += src[ct * 4 + r];
    }

    float bv = bptr[0];
    float sc[5]; unsigned ab[5];
#pragma unroll
    for (int ct = 0; ct < 5; ++ct) { sc[ct] = scale[ct * 16 + col]; ab[ct] = act[ct]; }

    float contrib = 0.f;
#pragma unroll
    for (int reg = 0; reg < 4; ++reg) {
        int rl = q * 4 + reg;
        int row = rowbase + rl;
        float inv = 1.0f / fmaxf(sqrtf(xn2[p * 16 + rl]), 1e-8f);
        unsigned long long mask = masks[row];
        float v[5]; float lmax = -1e30f;
#pragma unroll
        for (int ct = 0; ct < 5; ++ct) {
            float lg = acc[ct][reg] * sc[ct] * inv + bv;   // w*cos + b
            bool a = (ab[ct] >> col) & 1u;
            v[ct] = a ? lg : -1e30f;
            lmax = fmaxf(lmax, v[ct]);
        }
#pragma unroll
        for (int m = 1; m < 16; m <<= 1) lmax = fmaxf(lmax, __shfl_xor(lmax, m, 16));
        float es = 0.f;
#pragma unroll
        for (int ct = 0; ct < 5; ++ct) es += expf(v[ct] - lmax);
#pragma unroll
        for (int m = 1; m < 16; m <<= 1) es += __shfl_xor(es, m, 16);
        float lse = lmax + logf(es);
        float ps = 0.f;
#pragma unroll
        for (int ct = 0; ct < 5; ++ct) {
            int c = ct * 16 + col;
            bool pos = (c < 64) ? (((mask >> c) & 1ull) != 0ull)
                                : ((c == 64) ? (mask == 0ull) : false);
            ps += pos ? v[ct] : 0.f;
        }
#pragma unroll
        for (int m = 1; m < 16; m <<= 1) ps += __shfl_xor(ps, m, 16);
        float npos = mask ? (float)__popcll(mask) : 1.0f;
        float crow = ps - npos * lse;
        if (col == 0) contrib += crow;
    }
#pragma unroll
    for (int m = 1; m < 64; m <<= 1) contrib += __shfl_xor(contrib, m, 64);
    if (lane == 0) atomicAdd(wsum, contrib);
}

// ---- K4: loss = -sum(logp over positive pairs) / n_pairs ----
__global__ void k4_final(const unsigned* __restrict__ counts,
                         const float* __restrict__ wsum,
                         float* __restrict__ out) {
    if (threadIdx.x == 0 && blockIdx.x == 0) {
        float np = 0.f;
        for (int c = 0; c < NC; ++c) np += (float)counts[c];
        out[0] = -wsum[0] / np;
    }
}

extern "C" void kernel_launch(void* const* d_in, const int* in_sizes, int n_in,
                              void* d_out, int out_size, void* d_ws, size_t ws_size,
                              hipStream_t stream) {
    (void)in_sizes; (void)n_in; (void)out_size;
    const float* x = (const float*)d_in[0];
    const int* label = (const int*)d_in[1];
    const float* w = (const float*)d_in[2];
    const float* b = (const float*)d_in[3];

    char* ws = (char*)d_ws;
    unsigned* counts = (unsigned*)(ws + CNT_B);
    unsigned* act = (unsigned*)(ws + ACT_B);
    float* scale = (float*)(ws + SCALE_B);
    float* wsum = (float*)(ws + WSUM_B);
    unsigned long long* masks = (unsigned long long*)(ws + MASK_B);
    unsigned short* abf = (unsigned short*)(ws + ABF_B);
    unsigned short* labT = (unsigned short*)(ws + LABT_B);
    float* partial = (float*)(ws + PART_B);

    int kslices = 32;   // partial slabs; shrink if workspace is small
    while (kslices > 8 && PART_B + (size_t)kslices * CPAD * NDIM * 4 > ws_size) kslices >>= 1;

    hipMemsetAsync(d_ws, 0, ZERO_BYTES, stream);
    hipLaunchKernelGGL(k1_labels, dim3(256), dim3(256), 0, stream, label, masks, counts, labT);
    hipLaunchKernelGGL(k2_sums, dim3(16 * kslices), dim3(256), 0, stream, x, labT, partial, kslices);
    hipLaunchKernelGGL(k2b_norm, dim3(CPAD), dim3(256), 0, stream,
                       w, counts, partial, kslices, abf, scale, act);
    hipLaunchKernelGGL(k3_loss, dim3(NROWS / 32), dim3(256), 0, stream,
                       x, abf, masks, act, scale, b, wsum);
    hipLaunchKernelGGL(k4_final, dim3(1), dim3(64), 0, stream, counts, wsum, (float*)d_out);
}